// Round 1
// baseline (576.334 us; speedup 1.0000x reference)
//
#include <hip/hip_runtime.h>
#include <hip/hip_bf16.h>
#include <stdint.h>

// Problem constants
#define N_ROWS 65536
#define DIM 1024
#define SDIM 200
#define NCOLS 525          // 1 + 200 + 324 combined output columns
#define SCORE_COLS 81
#define BBOX_COLS 324
#define WB_ROWS 640        // padded to 5 col-tiles of 128
#define OUT_BBOX_OFF ((size_t)N_ROWS * SCORE_COLS)

typedef __attribute__((ext_vector_type(8))) short short8;
typedef __attribute__((ext_vector_type(8))) __bf16 bf16x8;
typedef __attribute__((ext_vector_type(4))) float floatx4;

// f32 -> bf16 (round-half-up; bias negligible vs 2% tolerance), pack 2 into u32
__device__ inline unsigned pack2_bf16(float a, float b) {
  unsigned ua = __builtin_bit_cast(unsigned, a) + 0x8000u;
  unsigned ub = __builtin_bit_cast(unsigned, b) + 0x8000u;
  return (ua >> 16) | (ub & 0xFFFF0000u);
}

#define GLD16(g, l) __builtin_amdgcn_global_load_lds( \
    (const __attribute__((address_space(1))) void*)(g), \
    (__attribute__((address_space(3))) void*)(l), 16, 0, 0)

// ---------------- kernel 0: weights f32 -> bf16, combined + padded ----------
__global__ __launch_bounds__(256) void prep_kernel(
    const float* __restrict__ W_cls, const float* __restrict__ b_cls,
    const float* __restrict__ W_sem, const float* __restrict__ b_sem,
    const float* __restrict__ W_bbox, const float* __restrict__ b_bbox,
    unsigned short* __restrict__ Wb, float* __restrict__ biasc)
{
  int w = blockIdx.x;          // 0..639 combined weight row
  int t = threadIdx.x;         // 256 threads, 4 f32 each
  const float* src = nullptr;
  float bv = 0.f;
  if (w == 0)        { src = W_cls;                        bv = b_cls[0]; }
  else if (w <= 200) { src = W_sem  + (size_t)(w-1)*DIM;   bv = b_sem[w-1]; }
  else if (w < 525)  { src = W_bbox + (size_t)(w-201)*DIM; bv = b_bbox[w-201]; }
  unsigned u0 = 0, u1 = 0;
  if (src) {
    float4 v = *(const float4*)(src + t*4);
    u0 = pack2_bf16(v.x, v.y);
    u1 = pack2_bf16(v.z, v.w);
  }
  *(uint2*)(Wb + (size_t)w*DIM + t*4) = make_uint2(u0, u1);
  if (t == 0) biasc[w] = bv;
}

// ---------------- kernel 1: 128x128-tile bf16 MFMA GEMM ---------------------
// A = x[65536,1024] f32 (converted in staging), B^T = Wb[640,1024] bf16.
// LDS: As 128 rows x 80B (32 bf16 + 8 pad -> 2-way banks = free)
//      Bs 128 cols x 64B, 16B segments swizzled s = ((col>>1)+q)&3 (2-way)
__global__ __launch_bounds__(256, 3) void gemm_kernel(
    const float* __restrict__ x, const unsigned short* __restrict__ Wb,
    const float* __restrict__ biasc, float* __restrict__ out,
    float* __restrict__ sem_ws)
{
  __shared__ __align__(16) unsigned char lds[10240 + 8192];
  unsigned char* As = lds;
  unsigned char* Bs = lds + 10240;

  const int t = threadIdx.x;
  const int bid = blockIdx.x;
  const int ct = bid % 5;            // col tile fastest -> same x row-tile
  const int rt = bid / 5;            //   adjacent in dispatch (L2/L3 reuse)
  const int rowbase = rt << 7;
  const int colbase = ct << 7;

  const int lane = t & 63;
  const int quad = lane >> 4;
  const int l15 = lane & 15;
  const int wm = t >> 7;             // 2x2 wave grid, 64x64 per wave
  const int wn = (t >> 6) & 1;

  floatx4 acc[4][4] = {};

  const int arow = t >> 2;           // A staging: 8 f32 per thread per j
  const int ac8 = t & 3;
  const float* xa = x + (size_t)(rowbase + arow) * DIM + ac8 * 8;

  const int bcol = t >> 2;           // B staging: one 16B seg per thread per j
  const int bs = t & 3;

  for (int kt = 0; kt < DIM/32; ++kt) {
    // B: global bf16 -> LDS direct (zero VALU), swizzled segment fetch
    {
      int col0 = bcol;
      int g0 = (bs - (col0 >> 1)) & 3;
      GLD16(Wb + (size_t)(colbase + col0) * DIM + kt*32 + g0*8,
            Bs + ((t >> 6) << 10));
      int col1 = bcol + 64;
      int g1 = (bs - (col1 >> 1)) & 3;
      GLD16(Wb + (size_t)(colbase + col1) * DIM + kt*32 + g1*8,
            Bs + ((t >> 6) << 10) + 4096);
    }
    // A: f32 load (2x dwordx4) -> bf16 pack -> ds_write_b128
#pragma unroll
    for (int j = 0; j < 2; ++j) {
      const float* p = xa + (size_t)j * 64 * DIM + kt * 32;
      float4 v0 = *(const float4*)p;
      float4 v1 = *(const float4*)(p + 4);
      uint4 u;
      u.x = pack2_bf16(v0.x, v0.y);
      u.y = pack2_bf16(v0.z, v0.w);
      u.z = pack2_bf16(v1.x, v1.y);
      u.w = pack2_bf16(v1.z, v1.w);
      *(uint4*)(As + (arow + j*64) * 80 + ac8 * 16) = u;
    }
    __syncthreads();

    short8 a8[4], b8[4];
#pragma unroll
    for (int mi = 0; mi < 4; ++mi)
      a8[mi] = *(const short8*)(As + (wm*64 + mi*16 + l15) * 80 + quad * 16);
#pragma unroll
    for (int ni = 0; ni < 4; ++ni) {
      int col = wn*64 + ni*16 + l15;
      int s2 = ((col >> 1) + quad) & 3;
      b8[ni] = *(const short8*)(Bs + col * 64 + s2 * 16);
    }
#pragma unroll
    for (int mi = 0; mi < 4; ++mi)
#pragma unroll
      for (int ni = 0; ni < 4; ++ni)
        acc[mi][ni] = __builtin_amdgcn_mfma_f32_16x16x32_bf16(
            __builtin_bit_cast(bf16x8, a8[mi]),
            __builtin_bit_cast(bf16x8, b8[ni]), acc[mi][ni], 0, 0, 0);
    __syncthreads();
  }

  // Epilogue: C/D layout col=lane&15, row=quad*4+reg (m89-verified)
#pragma unroll
  for (int ni = 0; ni < 4; ++ni) {
    int c = colbase + wn*64 + ni*16 + l15;
    if (c >= NCOLS) continue;
    float bias = biasc[c];
#pragma unroll
    for (int mi = 0; mi < 4; ++mi) {
#pragma unroll
      for (int r = 0; r < 4; ++r) {
        int row = rowbase + wm*64 + mi*16 + quad*4 + r;
        float v = acc[mi][ni][r] + bias;
        if (c == 0)         out[(size_t)row * SCORE_COLS] = v;            // b_score
        else if (c <= SDIM) sem_ws[(size_t)row * SDIM + (c-1)] = v;       // sem
        else                out[OUT_BBOX_OFF + (size_t)row * BBOX_COLS + (c-201)] = v;
      }
    }
  }
}

// ---------------- kernel 2: masked cls columns ------------------------------
// Only 12 of 80 columns are nonzero: IGNORE2-1 plus col 79 (live == detached fwd)
__device__ const int ACT[12] = {1,2,16,18,29,37,47,53,63,68,72,79};

__global__ __launch_bounds__(256) void cls_kernel(
    const float* __restrict__ sem_ws, const float* __restrict__ sm,
    float* __restrict__ out)
{
  __shared__ float semt[32 * SDIM];
  __shared__ float sma[12 * SDIM];
  const int t = threadIdx.x;
  const int rowbase = blockIdx.x * 32;

  const float4* src = (const float4*)(sem_ws + (size_t)rowbase * SDIM);
  float4* dst = (float4*)semt;
  for (int i = t; i < 32*SDIM/4; i += 256) dst[i] = src[i];
  for (int i = t; i < 12*SDIM; i += 256) {
    int a = i / SDIM, s = i - a*SDIM;
    sma[i] = sm[(size_t)ACT[a]*SDIM + s] * (1.0f/SDIM);
  }
  __syncthreads();

  const unsigned long long MLO =
      (1ULL<<1)|(1ULL<<2)|(1ULL<<16)|(1ULL<<18)|(1ULL<<29)|(1ULL<<37)|
      (1ULL<<47)|(1ULL<<53)|(1ULL<<63);
  const unsigned MHI = (1u<<(68-64))|(1u<<(72-64))|(1u<<(79-64));
  for (int i = t; i < 32*80; i += 256) {
    int row = i / 80, col = i - row*80;
    bool act = (col < 64) ? ((MLO >> col) & 1ULL) : ((MHI >> (col-64)) & 1u);
    if (!act) out[(size_t)(rowbase+row)*SCORE_COLS + 1 + col] = 0.f;
  }
  for (int i = t; i < 32*12; i += 256) {
    int row = i / 12, a = i - row*12;
    const float4* sr = (const float4*)(semt + row*SDIM);
    const float4* wr = (const float4*)(sma + a*SDIM);
    float accv = 0.f;
#pragma unroll 5
    for (int q = 0; q < SDIM/4; ++q) {
      float4 aa = sr[q], bb = wr[q];
      accv += aa.x*bb.x + aa.y*bb.y + aa.z*bb.z + aa.w*bb.w;
    }
    out[(size_t)(rowbase+row)*SCORE_COLS + 1 + ACT[a]] = accv;
  }
}

// ---------------- launcher --------------------------------------------------
extern "C" void kernel_launch(void* const* d_in, const int* in_sizes, int n_in,
                              void* d_out, int out_size, void* d_ws, size_t ws_size,
                              hipStream_t stream) {
  const float* x      = (const float*)d_in[0];
  const float* W_cls  = (const float*)d_in[1];
  const float* b_cls  = (const float*)d_in[2];
  const float* W_sem  = (const float*)d_in[3];
  const float* b_sem  = (const float*)d_in[4];
  const float* W_bbox = (const float*)d_in[5];
  const float* b_bbox = (const float*)d_in[6];
  const float* smat   = (const float*)d_in[7];
  float* out = (float*)d_out;

  // ws layout: Wb bf16 [640*1024] = 1,310,720 B; biasc [640] f32; sem [N,200] f32
  unsigned short* Wb = (unsigned short*)d_ws;
  float* biasc  = (float*)((char*)d_ws + 1310720);
  float* sem_ws = (float*)((char*)d_ws + 1313792);

  hipLaunchKernelGGL(prep_kernel, dim3(WB_ROWS), dim3(256), 0, stream,
                     W_cls, b_cls, W_sem, b_sem, W_bbox, b_bbox, Wb, biasc);
  hipLaunchKernelGGL(gemm_kernel, dim3(512*5), dim3(256), 0, stream,
                     x, Wb, biasc, out, sem_ws);
  hipLaunchKernelGGL(cls_kernel, dim3(N_ROWS/32), dim3(256), 0, stream,
                     sem_ws, smat, out);
}

// Round 2
// 506.518 us; speedup vs baseline: 1.1378x; 1.1378x over previous
//
#include <hip/hip_runtime.h>
#include <hip/hip_bf16.h>
#include <stdint.h>

// Problem constants
#define N_ROWS 65536
#define DIM 1024
#define SDIM 200
#define SCORE_COLS 81
#define BBOX_COLS 324
#define GEMM_COLS 384      // 1 (cls) + 12 (folded sem->cls) + 324 (bbox) + pad
#define OUT_BBOX_OFF ((size_t)N_ROWS * SCORE_COLS)

typedef __attribute__((ext_vector_type(8))) short short8;
typedef __attribute__((ext_vector_type(8))) __bf16 bf16x8;
typedef __attribute__((ext_vector_type(4))) float floatx4;

// Active cls columns: IGNORE2 - 1, plus 79 (live col == detached col forward)
__device__ const int ACT[12] = {1,2,16,18,29,37,47,53,63,68,72,79};

// f32 -> bf16 (round-half-up), pack 2 into u32
__device__ inline unsigned pack2_bf16(float a, float b) {
  unsigned ua = __builtin_bit_cast(unsigned, a) + 0x8000u;
  unsigned ub = __builtin_bit_cast(unsigned, b) + 0x8000u;
  return (ua >> 16) | (ub & 0xFFFF0000u);
}
__device__ inline unsigned short to_bf16(float a) {
  return (unsigned short)((__builtin_bit_cast(unsigned, a) + 0x8000u) >> 16);
}

#define GLD16(g, l) __builtin_amdgcn_global_load_lds( \
    (const __attribute__((address_space(1))) void*)(g), \
    (__attribute__((address_space(3))) void*)(l), 16, 0, 0)

// ---- prep 1: pack W_cls / W_bbox / zero-pad into Wb (cols 1..12 by prep 2) --
__global__ __launch_bounds__(256) void prep_w_kernel(
    const float* __restrict__ W_cls, const float* __restrict__ b_cls,
    const float* __restrict__ W_bbox, const float* __restrict__ b_bbox,
    unsigned short* __restrict__ Wb, float* __restrict__ biasc)
{
  int c = blockIdx.x;          // GEMM column 0..383
  int t = threadIdx.x;
  if (c >= 1 && c <= 12) return;   // W_eff columns, written by prep_eff
  const float* src = nullptr;
  float bv = 0.f;
  if (c == 0)                  { src = W_cls;                        bv = b_cls[0]; }
  else if (c >= 13 && c < 337) { src = W_bbox + (size_t)(c-13)*DIM;  bv = b_bbox[c-13]; }
  unsigned u0 = 0, u1 = 0;
  if (src) {
    float4 v = *(const float4*)(src + t*4);
    u0 = pack2_bf16(v.x, v.y);
    u1 = pack2_bf16(v.z, v.w);
  }
  *(uint2*)(Wb + (size_t)c*DIM + t*4) = make_uint2(u0, u1);
  if (t == 0) biasc[c] = bv;
}

// ---- prep 2: W_eff[a][k] = sum_s sm[ACT[a]][s]/200 * W_sem[s][k] -----------
__global__ __launch_bounds__(1024) void prep_eff_kernel(
    const float* __restrict__ W_sem, const float* __restrict__ b_sem,
    const float* __restrict__ sm,
    unsigned short* __restrict__ Wb, float* __restrict__ biasc)
{
  __shared__ float red[256];
  const int a = blockIdx.x;        // 0..11
  const int k = threadIdx.x;       // 0..1023
  const float* smrow = sm + (size_t)ACT[a]*SDIM;
  float acc = 0.f;
#pragma unroll 4
  for (int s = 0; s < SDIM; ++s)
    acc += smrow[s] * W_sem[(size_t)s*DIM + k];
  Wb[(size_t)(1+a)*DIM + k] = to_bf16(acc * (1.0f/SDIM));

  if (k < 200) red[k] = smrow[k] * b_sem[k];
  else if (k < 256) red[k] = 0.f;
  __syncthreads();
  if (k == 0) {
    float b = 0.f;
    for (int s = 0; s < 256; ++s) b += red[s];
    biasc[1+a] = b * (1.0f/SDIM);
  }
}

// ---- GEMM: 64 rows x 384 cols per block, 4 waves at 64x96 ------------------
// A = x[65536,1024] f32 (bf16-converted in staging); B^T = Wb[384,1024] bf16.
// x is read exactly once (each block owns all 384 cols of its 64-row tile);
// Wb (768 KB) is re-read by every block but lives in L2.
__global__ __launch_bounds__(256, 3) void gemm_kernel(
    const float* __restrict__ x, const unsigned short* __restrict__ Wb,
    const float* __restrict__ biasc, float* __restrict__ out)
{
  __shared__ __align__(16) unsigned char lds[5120 + 24576];
  unsigned char* As = lds;            // 64 rows x (32 bf16 + 8 pad) = 80 B
  unsigned char* Bs = lds + 5120;     // 384 cols x 64 B, 16B segs swizzled

  const int t = threadIdx.x;
  const int rowbase = blockIdx.x << 6;

  const int lane = t & 63;
  const int quad = lane >> 4;
  const int l15 = lane & 15;
  const int w = t >> 6;               // wave 0..3, cols [w*96, w*96+96)

  floatx4 acc[4][6] = {};

  const int arow = t >> 2;            // A staging: 8 f32 -> 16B bf16 per thread
  const int aseg = t & 3;
  const float* xa = x + (size_t)(rowbase + arow) * DIM + aseg * 8;

  const int bs = t & 3;               // B staging: 6 segs per thread
  const int bc = t >> 2;

  for (int kt = 0; kt < DIM/32; ++kt) {
    // B: global bf16 -> LDS direct; segment swizzle g = (s - (col>>1)) & 3
#pragma unroll
    for (int i = 0; i < 6; ++i) {
      int col = i*64 + bc;
      int g = (bs - (col >> 1)) & 3;
      GLD16(Wb + (size_t)col * DIM + kt*32 + g*8,
            Bs + i*4096 + w*1024);
    }
    // A: f32 dwordx4 x2 -> bf16 pack -> ds_write_b128
    {
      const float* p = xa + kt * 32;
      float4 v0 = *(const float4*)p;
      float4 v1 = *(const float4*)(p + 4);
      uint4 u;
      u.x = pack2_bf16(v0.x, v0.y);
      u.y = pack2_bf16(v0.z, v0.w);
      u.z = pack2_bf16(v1.x, v1.y);
      u.w = pack2_bf16(v1.z, v1.w);
      *(uint4*)(As + arow * 80 + aseg * 16) = u;
    }
    __syncthreads();

    short8 a8[4], b8[6];
#pragma unroll
    for (int mi = 0; mi < 4; ++mi)
      a8[mi] = *(const short8*)(As + (mi*16 + l15) * 80 + quad * 16);
#pragma unroll
    for (int ni = 0; ni < 6; ++ni) {
      int col = w*96 + ni*16 + l15;
      int s2 = ((col >> 1) + quad) & 3;
      b8[ni] = *(const short8*)(Bs + col * 64 + s2 * 16);
    }
#pragma unroll
    for (int ni = 0; ni < 6; ++ni)
#pragma unroll
      for (int mi = 0; mi < 4; ++mi)
        acc[mi][ni] = __builtin_amdgcn_mfma_f32_16x16x32_bf16(
            __builtin_bit_cast(bf16x8, a8[mi]),
            __builtin_bit_cast(bf16x8, b8[ni]), acc[mi][ni], 0, 0, 0);
    __syncthreads();
  }

  // Epilogue: C/D layout col=lane&15, row=quad*4+reg
#pragma unroll
  for (int ni = 0; ni < 6; ++ni) {
    int c = w*96 + ni*16 + l15;
    if (c >= 337) continue;
    float bias = biasc[c];
    int outcol = (c == 0) ? 0 : (c <= 12 ? 1 + ACT[c-1] : c - 13);
#pragma unroll
    for (int mi = 0; mi < 4; ++mi) {
#pragma unroll
      for (int r = 0; r < 4; ++r) {
        int row = rowbase + mi*16 + quad*4 + r;
        float v = acc[mi][ni][r] + bias;
        if (c <= 12) out[(size_t)row * SCORE_COLS + outcol] = v;
        else         out[OUT_BBOX_OFF + (size_t)row * BBOX_COLS + outcol] = v;
      }
    }
  }

  // Zero-fill the 68 dead score columns for this block's 64 rows
  const unsigned long long MLO =
      (1ULL<<1)|(1ULL<<2)|(1ULL<<16)|(1ULL<<18)|(1ULL<<29)|(1ULL<<37)|
      (1ULL<<47)|(1ULL<<53)|(1ULL<<63);
  const unsigned MHI = (1u<<(68-64))|(1u<<(72-64))|(1u<<(79-64));
  for (int i = t; i < 64*80; i += 256) {
    int row = i / 80, col = i - row*80;
    bool act = (col < 64) ? ((MLO >> col) & 1ULL) : ((MHI >> (col-64)) & 1u);
    if (!act) out[(size_t)(rowbase+row) * SCORE_COLS + 1 + col] = 0.f;
  }
}

// ---------------- launcher --------------------------------------------------
extern "C" void kernel_launch(void* const* d_in, const int* in_sizes, int n_in,
                              void* d_out, int out_size, void* d_ws, size_t ws_size,
                              hipStream_t stream) {
  const float* x      = (const float*)d_in[0];
  const float* W_cls  = (const float*)d_in[1];
  const float* b_cls  = (const float*)d_in[2];
  const float* W_sem  = (const float*)d_in[3];
  const float* b_sem  = (const float*)d_in[4];
  const float* W_bbox = (const float*)d_in[5];
  const float* b_bbox = (const float*)d_in[6];
  const float* smat   = (const float*)d_in[7];
  float* out = (float*)d_out;

  // ws layout: Wb bf16 [384*1024] = 786432 B; biasc [384] f32
  unsigned short* Wb = (unsigned short*)d_ws;
  float* biasc = (float*)((char*)d_ws + 786432);

  hipLaunchKernelGGL(prep_w_kernel, dim3(GEMM_COLS), dim3(256), 0, stream,
                     W_cls, b_cls, W_bbox, b_bbox, Wb, biasc);
  hipLaunchKernelGGL(prep_eff_kernel, dim3(12), dim3(1024), 0, stream,
                     W_sem, b_sem, smat, Wb, biasc);
  hipLaunchKernelGGL(gemm_kernel, dim3(N_ROWS/64), dim3(256), 0, stream,
                     x, Wb, biasc, out);
}